// Round 16
// baseline (92.119 us; speedup 1.0000x reference)
//
#include <hip/hip_runtime.h>

#define NUM_CLASSES 80
#define R1 8            // REG_MAX + 1
#define HW 4096         // H*W
#define CPG 20          // cls channels per sweep group (4 groups)

// fast hardware transcendentals (outputs are sums of 262K O(1) terms,
// absmax threshold 122.88 -- 2-ulp native math is noise)
__device__ __forceinline__ float fexp(float x) { return __expf(x); }
__device__ __forceinline__ float flog(float x) { return __logf(x); }
__device__ __forceinline__ float frcp(float x) { return __builtin_amdgcn_rcpf(x); }

__device__ __forceinline__ void cls1(float x, float& xm, float& ns) {
    xm = fmaxf(xm, x);
    float e  = fexp(-x);            // exp(-x)
    float s  = frcp(1.0f + e);      // sigmoid
    float sp = x - flog(s);         // softplus(x)
    ns = fmaf(sp * s, s, ns);
}

// =====================================================================
// Kernel 1: LINEAR sweep. Each block reads one fully-contiguous region
// (m13 pattern), decoding channel/anchor from the flat offset.
//   blocks [0, nClsBlk):  (image b, cls group g) -> 20 ch x 16 KB = 320 KB
//   blocks [nClsBlk, ..): (image b, side s)      ->  8 ch x 16 KB = 128 KB
// Thread t owns 8 fixed anchors: {4t..4t+3} and {2048+4t..} per image.
// Partials -> W: [2g+0]=negsum, [2g+1]=xmax (g=0..3);
//               [8+2s]=corner, [9+2s]=dfl-term (s=0..3). 16 x N floats.
// =====================================================================
__global__ __launch_bounds__(512)
__attribute__((amdgpu_waves_per_eu(2, 4)))   // min=2 keeps allocator unpinned
void sweep_kernel(const float* __restrict__ cls_score,
                  const float* __restrict__ bbox_pred,
                  const float* __restrict__ anchors,
                  const float* __restrict__ bbox_targets,
                  const int*   __restrict__ stride_p,
                  float* __restrict__ W,
                  int nClsBlk, int N)
{
    const int t   = threadIdx.x;
    const int blk = blockIdx.x;

    if (blk < nClsBlk) {
        // ---------------- cls sweep: 40 iterations of 8 KB ----------------
        const int b = blk >> 2, g = blk & 3;
        const float* base = cls_score + ((size_t)b * NUM_CLASSES + (size_t)g * CPG) * HW;

        float ns[2][4], xm[2][4];
        #pragma unroll
        for (int hh = 0; hh < 2; ++hh)
            #pragma unroll
            for (int i = 0; i < 4; ++i) { ns[hh][i] = 0.0f; xm[hh][i] = -INFINITY; }

        float4 buf[4];
        #pragma unroll
        for (int k = 0; k < 4; ++k)
            buf[k] = *(const float4*)(base + (size_t)k * 2048 + 4 * t);

        #pragma unroll
        for (int k = 0; k < 2 * CPG; ++k) {
            const float4 v = buf[k & 3];
            if (k + 4 < 2 * CPG)
                buf[k & 3] = *(const float4*)(base + (size_t)(k + 4) * 2048 + 4 * t);
            const int hh = k & 1;                 // compile-time under unroll
            cls1(v.x, xm[hh][0], ns[hh][0]);
            cls1(v.y, xm[hh][1], ns[hh][1]);
            cls1(v.z, xm[hh][2], ns[hh][2]);
            cls1(v.w, xm[hh][3], ns[hh][3]);
        }

        #pragma unroll
        for (int hh = 0; hh < 2; ++hh) {
            const size_t idx = (size_t)b * HW + (size_t)hh * 2048 + 4 * t;
            *(float4*)&W[(size_t)(2 * g + 0) * N + idx] =
                make_float4(ns[hh][0], ns[hh][1], ns[hh][2], ns[hh][3]);
            *(float4*)&W[(size_t)(2 * g + 1) * N + idx] =
                make_float4(xm[hh][0], xm[hh][1], xm[hh][2], xm[hh][3]);
        }
    } else {
        // ---------------- box sweep: 16 iterations, online softmax ----------------
        const int blk2 = blk - nClsBlk;
        const int b = blk2 >> 2, s = blk2 & 3;    // side s, block-uniform
        const float* base = bbox_pred + ((size_t)b * 32 + (size_t)s * 8) * HW;
        const float inv_str = frcp((float)stride_p[0]);

        int   tli[2][4];
        float wl[2][4], wr[2][4];
        #pragma unroll
        for (int hh = 0; hh < 2; ++hh) {
            #pragma unroll
            for (int i = 0; i < 4; ++i) {
                const int nn = b * HW + hh * 2048 + 4 * t + i;
                const float4 a  = ((const float4*)anchors)[nn];
                const float4 tt = ((const float4*)bbox_targets)[nn];
                const float cx = 0.5f * (a.x + a.z) * inv_str;
                const float cy = 0.5f * (a.y + a.w) * inv_str;
                const float dd = (s == 0) ? (cx - tt.x * inv_str)
                               : (s == 1) ? (cy - tt.y * inv_str)
                               : (s == 2) ? (tt.z * inv_str - cx)
                                          : (tt.w * inv_str - cy);
                const float d = fminf(fmaxf(dd, 0.0f), (float)(R1 - 1) - 0.1f);
                const int tl = (int)d;            // d >= 0: floor == trunc
                tli[hh][i] = tl;
                wl[hh][i]  = (float)(tl + 1) - d;
                wr[hh][i]  = d - (float)tl;
            }
        }

        float m[2][4], se[2][4], swe[2][4], xtl[2][4], xtr[2][4];
        #pragma unroll
        for (int hh = 0; hh < 2; ++hh)
            #pragma unroll
            for (int i = 0; i < 4; ++i) {
                m[hh][i] = -INFINITY; se[hh][i] = 0.0f; swe[hh][i] = 0.0f;
                xtl[hh][i] = 0.0f; xtr[hh][i] = 0.0f;
            }

        float4 buf[4];
        #pragma unroll
        for (int k = 0; k < 4; ++k)
            buf[k] = *(const float4*)(base + (size_t)k * 2048 + 4 * t);

        #pragma unroll
        for (int k = 0; k < 16; ++k) {
            const float4 v = buf[k & 3];
            if (k + 4 < 16)
                buf[k & 3] = *(const float4*)(base + (size_t)(k + 4) * 2048 + 4 * t);
            const int j  = k >> 1;                // bin, compile-time
            const int hh = k & 1;
            const float jf = (float)j;
            const float xs[4] = {v.x, v.y, v.z, v.w};
            #pragma unroll
            for (int i = 0; i < 4; ++i) {
                const float x = xs[i];
                if (j == tli[hh][i])     xtl[hh][i] = x;   // cndmask
                if (j == tli[hh][i] + 1) xtr[hh][i] = x;
                const float mn = fmaxf(m[hh][i], x);
                const float sc = fexp(m[hh][i] - mn);      // exp(-inf)=0 first pass
                const float e  = fexp(x - mn);
                se[hh][i]  = fmaf(se[hh][i], sc, e);
                swe[hh][i] = fmaf(swe[hh][i], sc, jf * e);
                m[hh][i] = mn;
            }
        }

        #pragma unroll
        for (int hh = 0; hh < 2; ++hh) {
            float cor[4], ds[4];
            #pragma unroll
            for (int i = 0; i < 4; ++i) {
                cor[i] = swe[hh][i] * frcp(se[hh][i]);
                const float lse = m[hh][i] + flog(se[hh][i]);
                ds[i] = (lse - xtl[hh][i]) * wl[hh][i]
                      + (lse - xtr[hh][i]) * wr[hh][i];
            }
            const size_t idx = (size_t)b * HW + (size_t)hh * 2048 + 4 * t;
            *(float4*)&W[(size_t)(8 + 2 * s) * N + idx] =
                make_float4(cor[0], cor[1], cor[2], cor[3]);
            *(float4*)&W[(size_t)(9 + 2 * s) * N + idx] =
                make_float4(ds[0], ds[1], ds[2], ds[3]);
        }
    }
}

// =====================================================================
// Kernel 2: per-anchor finalize (merge partials, GIoU/QFL/DFL, reduce)
// =====================================================================
__global__ __launch_bounds__(256)
void finalize_kernel(const float* __restrict__ anchors,
                     const float* __restrict__ cls_score,
                     const float* __restrict__ label_weights,
                     const float* __restrict__ bbox_targets,
                     const int*   __restrict__ labels,
                     const int*   __restrict__ nts_p,
                     const int*   __restrict__ stride_p,
                     const float* __restrict__ W,
                     float* __restrict__ out, int N)
{
    const int tid = threadIdx.x;
    const int n   = blockIdx.x * 256 + tid;
    const int b   = n >> 12;
    const int hw  = n & (HW - 1);

    const float inv_str = frcp((float)stride_p[0]);
    const float inv_nts = frcp((float)nts_p[0]);

    const int lab = labels[n];
    const bool pos = (lab >= 0) && (lab < NUM_CLASSES);
    const int lab_c = pos ? lab : 0;
    const float xlab = cls_score[((size_t)b * NUM_CLASSES + lab_c) * HW + hw];
    const float lw = label_weights[n];
    const float4 a = ((const float4*)anchors)[n];
    const float4 tt = ((const float4*)bbox_targets)[n];

    // merge cls partials
    const float ns  = W[n] + W[2 * (size_t)N + n] + W[4 * (size_t)N + n]
                    + W[6 * (size_t)N + n];
    const float xmv = fmaxf(fmaxf(W[(size_t)N + n], W[3 * (size_t)N + n]),
                            fmaxf(W[5 * (size_t)N + n], W[7 * (size_t)N + n]));
    const float c0 = W[ 8 * (size_t)N + n], d0s = W[ 9 * (size_t)N + n];
    const float c1 = W[10 * (size_t)N + n], d1s = W[11 * (size_t)N + n];
    const float c2 = W[12 * (size_t)N + n], d2s = W[13 * (size_t)N + n];
    const float c3 = W[14 * (size_t)N + n], d3s = W[15 * (size_t)N + n];
    const float dsum = d0s + d1s + d2s + d3s;

    const float cx  = 0.5f * (a.x + a.z) * inv_str;
    const float cy  = 0.5f * (a.y + a.w) * inv_str;
    const float tx0 = tt.x * inv_str, ty0 = tt.y * inv_str;
    const float tx1 = tt.z * inv_str, ty1 = tt.w * inv_str;

    const float wt = pos ? frcp(1.0f + fexp(-xmv)) : 0.0f;

    const float px0 = cx - c0, py0 = cy - c1;
    const float px1 = cx + c2, py1 = cy + c3;

    const float ilx = fmaxf(px0, tx0), ily = fmaxf(py0, ty0);
    const float irx = fminf(px1, tx1), iry = fminf(py1, ty1);
    const float iw = fmaxf(irx - ilx, 0.0f), ih = fmaxf(iry - ily, 0.0f);
    const float overlap = iw * ih;
    const float ap = (px1 - px0) * (py1 - py0);
    const float at = (tx1 - tx0) * (ty1 - ty0);
    const float uni = fmaxf(ap + at - overlap, 1e-6f);
    const float iou = overlap * frcp(uni);

    const float elx = fminf(px0, tx0), ely = fminf(py0, ty0);
    const float erx = fmaxf(px1, tx1), ery = fmaxf(py1, ty1);
    const float ew = fmaxf(erx - elx, 0.0f), eh = fmaxf(ery - ely, 0.0f);
    const float earea = fmaxf(ew * eh, 1e-6f);
    const float giou = iou - (earea - uni) * frcp(earea);

    const float score = pos ? iou : 0.0f;
    float row = ns;
    if (pos) {
        const float e  = fexp(-xlab);
        const float s  = frcp(1.0f + e);     // sigmoid(x_label)
        const float sp = xlab - flog(s);     // softplus(x_label)
        const float negterm = sp * s * s;
        const float sf = score - s;
        const float posl = (sp - xlab * score) * sf * sf;
        row = row - negterm + posl;
    }

    float v0 = row * lw * inv_nts;
    float v1 = (1.0f - giou) * wt * 2.0f;
    float v2 = dsum * wt * 0.0625f;     // 0.25 / 4
    float v3 = wt;

    #pragma unroll
    for (int off = 32; off > 0; off >>= 1) {
        v0 += __shfl_down(v0, off);
        v1 += __shfl_down(v1, off);
        v2 += __shfl_down(v2, off);
        v3 += __shfl_down(v3, off);
    }

    __shared__ float smr[4][4];
    const int w    = tid >> 6;
    const int lane = tid & 63;
    if (lane == 0) {
        smr[w][0] = v0; smr[w][1] = v1;
        smr[w][2] = v2; smr[w][3] = v3;
    }
    __syncthreads();
    if (tid == 0) {
        atomicAdd(&out[0], smr[0][0] + smr[1][0] + smr[2][0] + smr[3][0]);
        atomicAdd(&out[1], smr[0][1] + smr[1][1] + smr[2][1] + smr[3][1]);
        atomicAdd(&out[2], smr[0][2] + smr[1][2] + smr[2][2] + smr[3][2]);
        atomicAdd(&out[3], smr[0][3] + smr[1][3] + smr[2][3] + smr[3][3]);
    }
}

// =====================================================================
// Fallback (ws too small): proven single-kernel R2 path
// =====================================================================
__global__ __launch_bounds__(256) void fb_kernel(
    const float* __restrict__ anchors, const float* __restrict__ cls_score,
    const float* __restrict__ bbox_pred, const float* __restrict__ label_weights,
    const float* __restrict__ bbox_targets, const int* __restrict__ labels,
    const int* __restrict__ nts_p, const int* __restrict__ stride_p,
    float* __restrict__ out, int N)
{
    const int n = blockIdx.x * blockDim.x + threadIdx.x;
    const float inv_str = frcp((float)stride_p[0]);
    const float inv_nts = frcp((float)nts_p[0]);
    float qfl = 0.0f, lbbox = 0.0f, dfl = 0.0f, wts = 0.0f;
    if (n < N) {
        const int b = n >> 12, hw = n & (HW - 1);
        const int lab = labels[n];
        const bool pos = (lab >= 0) && (lab < NUM_CLASSES);
        const int lab_c = pos ? lab : 0;
        const float* cbase = cls_score + (size_t)b * NUM_CLASSES * HW + hw;
        float xmax = -INFINITY, negsum = 0.0f, xlab = 0.0f;
        #pragma unroll 16
        for (int c = 0; c < NUM_CLASSES; ++c) {
            float x = cbase[(size_t)c * HW];
            xmax = fmaxf(xmax, x);
            float e = fexp(-x); float s = frcp(1.0f + e);
            float sp = x - flog(s);
            negsum = fmaf(sp * s, s, negsum);
            if (c == lab_c) xlab = x;
        }
        const float wt = pos ? frcp(1.0f + fexp(-xmax)) : 0.0f;
        const float4 a = ((const float4*)anchors)[n];
        const float cx = 0.5f * (a.x + a.z) * inv_str;
        const float cy = 0.5f * (a.y + a.w) * inv_str;
        const float4 t = ((const float4*)bbox_targets)[n];
        const float tx0 = t.x * inv_str, ty0 = t.y * inv_str;
        const float tx1 = t.z * inv_str, ty1 = t.w * inv_str;
        float dist[4] = {cx - tx0, cy - ty0, tx1 - cx, ty1 - cy};
        const float* bbase = bbox_pred + (size_t)b * (4 * R1) * HW + hw;
        float corners[4]; float dsum = 0.0f;
        #pragma unroll
        for (int k = 0; k < 4; ++k) {
            float xk[R1]; float m = -INFINITY;
            #pragma unroll
            for (int j = 0; j < R1; ++j) {
                xk[j] = bbase[(size_t)(k * R1 + j) * HW];
                m = fmaxf(m, xk[j]);
            }
            float se = 0.0f, swe = 0.0f;
            #pragma unroll
            for (int j = 0; j < R1; ++j) {
                float e = fexp(xk[j] - m); se += e; swe = fmaf(e, (float)j, swe);
            }
            corners[k] = swe * frcp(se);
            const float lse = m + flog(se);
            float d = fminf(fmaxf(dist[k], 0.0f), (float)(R1 - 1) - 0.1f);
            int tl = (int)d; int tr = tl + 1; if (tr > R1 - 1) tr = R1 - 1;
            float x_tl = xk[0], x_tr = xk[0];
            #pragma unroll
            for (int j = 1; j < R1; ++j) {
                if (j == tl) x_tl = xk[j];
                if (j == tr) x_tr = xk[j];
            }
            dsum += (lse - x_tl) * ((float)(tl + 1) - d) + (lse - x_tr) * (d - (float)tl);
        }
        dfl = dsum * wt;
        const float px0 = cx - corners[0], py0 = cy - corners[1];
        const float px1 = cx + corners[2], py1 = cy + corners[3];
        const float ilx = fmaxf(px0, tx0), ily = fmaxf(py0, ty0);
        const float irx = fminf(px1, tx1), iry = fminf(py1, ty1);
        const float iw = fmaxf(irx - ilx, 0.0f), ih = fmaxf(iry - ily, 0.0f);
        const float overlap = iw * ih;
        const float ap = (px1 - px0) * (py1 - py0);
        const float at = (tx1 - tx0) * (ty1 - ty0);
        const float uni = fmaxf(ap + at - overlap, 1e-6f);
        const float iou = overlap * frcp(uni);
        const float elx = fminf(px0, tx0), ely = fminf(py0, ty0);
        const float erx = fmaxf(px1, tx1), ery = fmaxf(py1, ty1);
        const float ew = fmaxf(erx - elx, 0.0f), eh = fmaxf(ery - ely, 0.0f);
        const float earea = fmaxf(ew * eh, 1e-6f);
        const float giou = iou - (earea - uni) * frcp(earea);
        lbbox = (1.0f - giou) * wt; wts = wt;
        const float score = pos ? iou : 0.0f;
        float row = negsum;
        if (pos) {
            const float e = fexp(-xlab); const float s = frcp(1.0f + e);
            const float sp = xlab - flog(s);
            const float sf = score - s;
            row = row - sp * s * s + (sp - xlab * score) * sf * sf;
        }
        qfl = row * label_weights[n];
    }
    float v0 = qfl * inv_nts, v1 = lbbox * 2.0f, v2 = dfl * 0.0625f, v3 = wts;
    #pragma unroll
    for (int off = 32; off > 0; off >>= 1) {
        v0 += __shfl_down(v0, off); v1 += __shfl_down(v1, off);
        v2 += __shfl_down(v2, off); v3 += __shfl_down(v3, off);
    }
    __shared__ float smr[4][4];
    const int wid = threadIdx.x >> 6, lane = threadIdx.x & 63;
    if (lane == 0) { smr[wid][0] = v0; smr[wid][1] = v1; smr[wid][2] = v2; smr[wid][3] = v3; }
    __syncthreads();
    if (threadIdx.x == 0) {
        atomicAdd(&out[0], smr[0][0] + smr[1][0] + smr[2][0] + smr[3][0]);
        atomicAdd(&out[1], smr[0][1] + smr[1][1] + smr[2][1] + smr[3][1]);
        atomicAdd(&out[2], smr[0][2] + smr[1][2] + smr[2][2] + smr[3][2]);
        atomicAdd(&out[3], smr[0][3] + smr[1][3] + smr[2][3] + smr[3][3]);
    }
}

extern "C" void kernel_launch(void* const* d_in, const int* in_sizes, int n_in,
                              void* d_out, int out_size, void* d_ws, size_t ws_size,
                              hipStream_t stream) {
    const float* anchors       = (const float*)d_in[0];
    const float* cls_score     = (const float*)d_in[1];
    const float* bbox_pred     = (const float*)d_in[2];
    const float* label_weights = (const float*)d_in[3];
    const float* bbox_targets  = (const float*)d_in[4];
    const int*   labels        = (const int*)d_in[5];
    const int*   nts_p         = (const int*)d_in[6];
    const int*   stride_p      = (const int*)d_in[7];
    float* out = (float*)d_out;

    const int N = in_sizes[5];  // labels count = B*H*W
    const int B = N / HW;

    hipMemsetAsync(d_out, 0, 4 * sizeof(float), stream);

    const size_t wsNeed = (size_t)16 * (size_t)N * sizeof(float);
    if (ws_size >= wsNeed) {
        float* W = (float*)d_ws;
        // K1: 4 cls-group blocks + 4 side blocks per image, all linear sweeps
        sweep_kernel<<<B * 8, 512, 0, stream>>>(
            cls_score, bbox_pred, anchors, bbox_targets, stride_p, W, B * 4, N);
        // K2: per-anchor finalize (stream order guarantees K1 visibility)
        finalize_kernel<<<N / 256, 256, 0, stream>>>(
            anchors, cls_score, label_weights, bbox_targets, labels,
            nts_p, stride_p, W, out, N);
    } else {
        fb_kernel<<<(N + 255) / 256, 256, 0, stream>>>(
            anchors, cls_score, bbox_pred, label_weights, bbox_targets,
            labels, nts_p, stride_p, out, N);
    }
}

// Round 17
// 73.657 us; speedup vs baseline: 1.2506x; 1.2506x over previous
//
#include <hip/hip_runtime.h>
#include <stdint.h>

#define NUM_CLASSES 80
#define R1 8            // REG_MAX + 1
#define HW 4096         // H*W
#define NG 28           // channel groups of 4: 20 cls + 8 box
#define RING 8          // LDS ring depth (groups); prefetch distance 7

// fast hardware transcendentals (outputs are sums of 262K O(1) terms,
// absmax threshold 122.88 -- 2-ulp native math is noise)
__device__ __forceinline__ float fexp(float x) { return __expf(x); }
__device__ __forceinline__ float flog(float x) { return __logf(x); }
__device__ __forceinline__ float frcp(float x) { return __builtin_amdgcn_rcpf(x); }

__device__ __forceinline__ void cls1(float x, float& xm, float& ns) {
    xm = fmaxf(xm, x);
    float e  = fexp(-x);            // exp(-x)
    float s  = frcp(1.0f + e);      // sigmoid
    float sp = x - flog(s);         // softplus(x)
    ns = fmaf(sp * s, s, ns);
}

// one bbox side: softmax-integral corner + DFL term
__device__ __forceinline__ void box8(const float (&xk)[8], float dk,
                                     float& corner, float& dsum) {
    float m = -INFINITY;
    #pragma unroll
    for (int j = 0; j < 8; ++j) m = fmaxf(m, xk[j]);
    float se = 0.0f, swe = 0.0f;
    #pragma unroll
    for (int j = 0; j < 8; ++j) {
        float e = fexp(xk[j] - m);
        se += e;
        swe = fmaf(e, (float)j, swe);
    }
    corner = swe * frcp(se);
    const float lse = m + flog(se);     // logsumexp

    // DFL: runtime bin -> unrolled compare-select (no scratch)
    float d = fminf(fmaxf(dk, 0.0f), (float)(R1 - 1) - 0.1f);
    int tl = (int)d;                    // d >= 0: floor == trunc
    int tr = tl + 1; if (tr > R1 - 1) tr = R1 - 1;
    float x_tl = xk[0], x_tr = xk[0];
    #pragma unroll
    for (int j = 1; j < 8; ++j) {
        if (j == tl) x_tl = xk[j];
        if (j == tr) x_tr = xk[j];
    }
    dsum += (lse - x_tl) * ((float)(tl + 1) - d) + (lse - x_tr) * (d - (float)tl);
}

// T3+T4: global_load_lds staging (zero VGPR cost) + counted vmcnt gates +
// raw s_barrier (never drains to vmcnt(0) in the main loop).
__global__ __launch_bounds__(256)
void nanodet_loss_kernel(
    const float* __restrict__ anchors,       // [N,4]
    const float* __restrict__ cls_score,     // [B,C,H,W]
    const float* __restrict__ bbox_pred,     // [B,4*R1,H,W]
    const float* __restrict__ label_weights, // [N]
    const float* __restrict__ bbox_targets,  // [N,4]
    const int*   __restrict__ labels,        // [N]
    const int*   __restrict__ nts_p,         // [1]
    const int*   __restrict__ stride_p,      // [1]
    float* __restrict__ out)
{
    __shared__ float ring[RING][4][256];     // 32 KB: 8 groups x 4 ch x 256 anchors

    const int tid  = threadIdx.x;
    const int w    = tid >> 6;               // wave 0..3
    const int lane = tid & 63;
    const int blk  = blockIdx.x;
    const int b    = blk >> 4;               // image
    const int hw0  = (blk & 15) * 256;       // anchor window start
    const int n    = blk * 256 + tid;        // this thread's anchor

    const float inv_str = frcp((float)stride_p[0]);
    const float inv_nts = frcp((float)nts_p[0]);

    const float* cls_u = cls_score + (size_t)b * NUM_CLASSES * HW + hw0;
    const float* box_u = bbox_pred + (size_t)b * 32 * HW + hw0;

    // ---- early scalar loads, fully consumed BEFORE staging begins (keeps
    //      the vmcnt queue = staging ops only) ----
    const int lab = labels[n];
    const bool pos = (lab >= 0) && (lab < NUM_CLASSES);
    const int lab_c = pos ? lab : 0;
    const float xlab = cls_u[(size_t)lab_c * HW + tid];
    const float lw = label_weights[n];
    const float4 a = ((const float4*)anchors)[n];
    const float4 t = ((const float4*)bbox_targets)[n];

    const float cx  = 0.5f * (a.x + a.z) * inv_str;
    const float cy  = 0.5f * (a.y + a.w) * inv_str;
    const float tx0 = t.x * inv_str, ty0 = t.y * inv_str;
    const float tx1 = t.z * inv_str, ty1 = t.w * inv_str;
    const float dist[4] = {cx - tx0, cy - ty0, tx1 - cx, ty1 - cy};

    // stage group g: wave w issues ONE global_load_lds of channel 4g+w's
    // 1 KB window (lane l -> 16 B) into ring[g&7][w][*]. No VGPR cost.
    auto stage = [&](int g) {                // g folds under #pragma unroll
        const float* base = (g < 20)
            ? cls_u + (size_t)(4 * g + w) * HW
            : box_u + (size_t)(4 * (g - 20) + w) * HW;
        const float* src = base + 4 * lane;
        auto gp = reinterpret_cast<const __attribute__((address_space(1))) void*>(
                      (uintptr_t)src);
        auto lp = reinterpret_cast<__attribute__((address_space(3))) void*>(
                      (uintptr_t)&ring[g & (RING - 1)][w][0]);
        __builtin_amdgcn_global_load_lds(gp, lp, 16, 0, 0);
    };

    float xm = -INFINITY, ns = 0.0f;
    float xk[8];
    float cor[4];
    float dsum = 0.0f;

    auto consume = [&](int p) {              // p folds under #pragma unroll
        #pragma unroll
        for (int j = 0; j < 4; ++j) {
            const float x = ring[p & (RING - 1)][j][tid];
            if (p < 20) {
                cls1(x, xm, ns);
            } else {
                const int half = (p - 20) & 1;       // compile-time
                xk[4 * half + j] = x;
            }
        }
        if (p >= 20 && ((p - 20) & 1)) {
            const int side = (p - 20) >> 1;          // compile-time
            box8(xk, dist[side], cor[side], dsum);
        }
    };

    // ---- prologue: fill 7 ring groups ----
    #pragma unroll
    for (int g = 0; g < RING - 1; ++g) stage(g);

    // ---- main loop: counted vmcnt(6), NEVER drains to 0 ----
    // gate retires exactly through group p's stage; barrier makes all 4
    // waves' stages for group p visible; stage targets slot (p-1)&7 (safe
    // after barrier); consume reads slot p&7.
    #pragma unroll
    for (int p = 0; p <= 20; ++p) {
        asm volatile("s_waitcnt vmcnt(6)" ::: "memory");
        __builtin_amdgcn_s_barrier();
        __builtin_amdgcn_sched_barrier(0);   // rule 18: pin reads after gate
        stage(p + RING - 1);                 // groups 7..27
        consume(p);                          // groups 0..20
    }
    // ---- tail: everything staged; one final drain ----
    asm volatile("s_waitcnt vmcnt(0)" ::: "memory");
    __builtin_amdgcn_s_barrier();
    __builtin_amdgcn_sched_barrier(0);
    #pragma unroll
    for (int p = 21; p < NG; ++p) consume(p);

    // ---------------- epilogue (per-lane, R2-proven) ----------------
    const float wt = pos ? frcp(1.0f + fexp(-xm)) : 0.0f;

    const float px0 = cx - cor[0], py0 = cy - cor[1];
    const float px1 = cx + cor[2], py1 = cy + cor[3];

    const float ilx = fmaxf(px0, tx0), ily = fmaxf(py0, ty0);
    const float irx = fminf(px1, tx1), iry = fminf(py1, ty1);
    const float iw = fmaxf(irx - ilx, 0.0f), ih = fmaxf(iry - ily, 0.0f);
    const float overlap = iw * ih;
    const float ap = (px1 - px0) * (py1 - py0);
    const float at = (tx1 - tx0) * (ty1 - ty0);
    const float uni = fmaxf(ap + at - overlap, 1e-6f);
    const float iou = overlap * frcp(uni);

    const float elx = fminf(px0, tx0), ely = fminf(py0, ty0);
    const float erx = fmaxf(px1, tx1), ery = fmaxf(py1, ty1);
    const float ew = fmaxf(erx - elx, 0.0f), eh = fmaxf(ery - ely, 0.0f);
    const float earea = fmaxf(ew * eh, 1e-6f);
    const float giou = iou - (earea - uni) * frcp(earea);

    const float score = pos ? iou : 0.0f;
    float row = ns;
    if (pos) {
        const float e  = fexp(-xlab);
        const float s  = frcp(1.0f + e);     // sigmoid(x_label)
        const float sp = xlab - flog(s);     // softplus(x_label)
        const float negterm = sp * s * s;
        const float sf = score - s;
        const float posl = (sp - xlab * score) * sf * sf;
        row = row - negterm + posl;
    }
    const float qfl = row * lw;

    // ---------------- reduction ----------------
    float v0 = qfl * inv_nts;
    float v1 = (1.0f - giou) * wt * 2.0f;
    float v2 = dsum * wt * 0.0625f;     // 0.25 / 4
    float v3 = wt;

    #pragma unroll
    for (int off = 32; off > 0; off >>= 1) {
        v0 += __shfl_down(v0, off);
        v1 += __shfl_down(v1, off);
        v2 += __shfl_down(v2, off);
        v3 += __shfl_down(v3, off);
    }

    __shared__ float smr[4][4];   // [wave][channel]
    if (lane == 0) {
        smr[w][0] = v0; smr[w][1] = v1;
        smr[w][2] = v2; smr[w][3] = v3;
    }
    __syncthreads();
    if (tid == 0) {
        float s0 = smr[0][0] + smr[1][0] + smr[2][0] + smr[3][0];
        float s1 = smr[0][1] + smr[1][1] + smr[2][1] + smr[3][1];
        float s2 = smr[0][2] + smr[1][2] + smr[2][2] + smr[3][2];
        float s3 = smr[0][3] + smr[1][3] + smr[2][3] + smr[3][3];
        atomicAdd(&out[0], s0);
        atomicAdd(&out[1], s1);
        atomicAdd(&out[2], s2);
        atomicAdd(&out[3], s3);
    }
}

extern "C" void kernel_launch(void* const* d_in, const int* in_sizes, int n_in,
                              void* d_out, int out_size, void* d_ws, size_t ws_size,
                              hipStream_t stream) {
    const float* anchors       = (const float*)d_in[0];
    const float* cls_score     = (const float*)d_in[1];
    const float* bbox_pred     = (const float*)d_in[2];
    const float* label_weights = (const float*)d_in[3];
    const float* bbox_targets  = (const float*)d_in[4];
    const int*   labels        = (const int*)d_in[5];
    const int*   nts_p         = (const int*)d_in[6];
    const int*   stride_p      = (const int*)d_in[7];
    float* out = (float*)d_out;

    const int N = in_sizes[5];  // labels count = B*H*W

    hipMemsetAsync(d_out, 0, 4 * sizeof(float), stream);

    const int block = 256;
    const int grid = N / block;               // 1024 blocks -> 4 blocks/CU
    nanodet_loss_kernel<<<grid, block, 0, stream>>>(
        anchors, cls_score, bbox_pred, label_weights, bbox_targets,
        labels, nts_p, stride_p, out);
}

// Round 18
// 43.990 us; speedup vs baseline: 2.0941x; 1.6744x over previous
//
#include <hip/hip_runtime.h>

#define NUM_CLASSES 80
#define CPH 40          // cls channels per half
#define R1 8            // REG_MAX + 1
#define HW 4096         // H*W
#define BLOCK 512       // threads per block (2 halves x 256)
#define APB 1024        // anchors per block (4 per thread, float4 loads)

// fast hardware transcendentals (outputs are sums of 262K O(1) terms,
// absmax threshold 122.88 -- 2-ulp native math is noise)
__device__ __forceinline__ float fexp(float x) { return __expf(x); }
__device__ __forceinline__ float flog(float x) { return __logf(x); }
__device__ __forceinline__ float frcp(float x) { return __builtin_amdgcn_rcpf(x); }

__device__ __forceinline__ void cls1(float x, float& xm, float& ns) {
    xm = fmaxf(xm, x);
    float e  = fexp(-x);            // exp(-x)
    float s  = frcp(1.0f + e);      // sigmoid
    float sp = x - flog(s);         // softplus(x)
    ns = fmaf(sp * s, s, ns);
}

// one bbox side for one anchor: softmax-integral corner + DFL term
__device__ __forceinline__ void box8(const float (&xk)[8], float dk,
                                     float& corner, float& dsum) {
    float m = -INFINITY;
    #pragma unroll
    for (int j = 0; j < 8; ++j) m = fmaxf(m, xk[j]);
    float se = 0.0f, swe = 0.0f;
    #pragma unroll
    for (int j = 0; j < 8; ++j) {
        float e = fexp(xk[j] - m);
        se += e;
        swe = fmaf(e, (float)j, swe);
    }
    corner = swe * frcp(se);
    const float lse = m + flog(se);     // logsumexp

    // DFL: runtime bin -> unrolled compare-select (no scratch)
    float d = fminf(fmaxf(dk, 0.0f), (float)(R1 - 1) - 0.1f);
    int tl = (int)d;                    // d >= 0: floor == trunc
    int tr = tl + 1; if (tr > R1 - 1) tr = R1 - 1;
    float x_tl = xk[0], x_tr = xk[0];
    #pragma unroll
    for (int j = 1; j < 8; ++j) {
        if (j == tl) x_tl = xk[j];
        if (j == tr) x_tr = xk[j];
    }
    dsum += (lse - x_tl) * ((float)(tl + 1) - d) + (lse - x_tr) * (d - (float)tl);
}

__global__ __launch_bounds__(BLOCK)
__attribute__((amdgpu_waves_per_eu(2, 2)))   // 256-VGPR budget: the only setting
                                             // that unpins the allocator from 64
void nanodet_loss_kernel(
    const float* __restrict__ anchors,       // [N,4]
    const float* __restrict__ cls_score,     // [B,C,H,W]
    const float* __restrict__ bbox_pred,     // [B,4*R1,H,W]
    const float* __restrict__ label_weights, // [N]
    const float* __restrict__ bbox_targets,  // [N,4]
    const int*   __restrict__ labels,        // [N]
    const int*   __restrict__ nts_p,         // [1]
    const int*   __restrict__ stride_p,      // [1]
    float* __restrict__ out)
{
    const int tib = threadIdx.x;
    const int h   = tib >> 8;                // half: 0 -> cls 0-39 / sides 0,1
    const int u   = tib & 255;               //       1 -> cls 40-79 / sides 2,3
    const int blk = blockIdx.x;
    const int b   = blk >> 2;                // image (uniform per block)
    const int hw0 = (blk & 3) * APB;         // window start (uniform)
    const int e   = 4 * u;                   // element offset in window
    const int n0  = blk * APB + e;           // first of this thread's 4 anchors

    const float inv_str = frcp((float)stride_p[0]);
    const float inv_nts = frcp((float)nts_p[0]);

    // block-half-uniform bases (SGPR) + per-thread element offset
    const float* cls_h = cls_score + (size_t)b * NUM_CLASSES * HW
                                   + (size_t)(h * CPH) * HW + hw0;
    const float* box_h = bbox_pred + (size_t)b * (4 * R1) * HW
                                   + (size_t)(h * 16) * HW + hw0;
    const uint32_t ue = (uint32_t)e;

    // ---- label load + label-logit gather ----
    const int4 lab4 = *(const int4*)(labels + n0);
    int labv[4] = {lab4.x, lab4.y, lab4.z, lab4.w};
    float xlab[4];
    #pragma unroll
    for (int i = 0; i < 4; ++i) {
        const int lc = labv[i];
        const bool own = (h == 0) ? (lc >= 0 && lc < CPH)
                                  : (lc >= CPH && lc < NUM_CLASSES);
        const int ch = own ? (lc - h * CPH) : 0;
        xlab[i] = cls_h[(uint32_t)ch * HW + ue + i];
    }

    // ---- cls sweep: 40 float4 channel loads, compiler-scheduled (~8 in
    //      flight; deeper is unreachable at HIP level, R13/R15/R17) ----
    float4 X[CPH];
    #pragma unroll
    for (int j = 0; j < CPH; ++j)
        X[j] = *reinterpret_cast<const float4*>(cls_h + (uint32_t)(j * HW) + ue);

    float xm[4] = {-INFINITY, -INFINITY, -INFINITY, -INFINITY};
    float ns[4] = {0.0f, 0.0f, 0.0f, 0.0f};

    // consume first 16 channels
    #pragma unroll
    for (int j = 0; j < 16; ++j) {
        cls1(X[j].x, xm[0], ns[0]);
        cls1(X[j].y, xm[1], ns[1]);
        cls1(X[j].z, xm[2], ns[2]);
        cls1(X[j].w, xm[3], ns[3]);
    }

    // issue this half's 16 box-channel loads
    float4 Xb[16];
    #pragma unroll
    for (int j = 0; j < 16; ++j)
        Xb[j] = *reinterpret_cast<const float4*>(box_h + (uint32_t)(j * HW) + ue);

    // issue geometry loads
    float4 a4[4], t4[4];
    #pragma unroll
    for (int i = 0; i < 4; ++i) {
        a4[i] = ((const float4*)anchors)[n0 + i];
        t4[i] = ((const float4*)bbox_targets)[n0 + i];
    }

    // consume remaining 24 cls channels
    #pragma unroll
    for (int j = 16; j < CPH; ++j) {
        cls1(X[j].x, xm[0], ns[0]);
        cls1(X[j].y, xm[1], ns[1]);
        cls1(X[j].z, xm[2], ns[2]);
        cls1(X[j].w, xm[3], ns[3]);
    }

    // geometry + this half's DFL distances
    float cx[4], cy[4], tx0[4], ty0[4], tx1[4], ty1[4], dk0[4], dk1[4];
    #pragma unroll
    for (int i = 0; i < 4; ++i) {
        cx[i]  = 0.5f * (a4[i].x + a4[i].z) * inv_str;
        cy[i]  = 0.5f * (a4[i].y + a4[i].w) * inv_str;
        tx0[i] = t4[i].x * inv_str; ty0[i] = t4[i].y * inv_str;
        tx1[i] = t4[i].z * inv_str; ty1[i] = t4[i].w * inv_str;
        dk0[i] = (h == 0) ? (cx[i] - tx0[i]) : (tx1[i] - cx[i]);
        dk1[i] = (h == 0) ? (cy[i] - ty0[i]) : (ty1[i] - cy[i]);
    }

    // box compute: side 2h from Xb[0..7], side 2h+1 from Xb[8..15]
    float corA[4], corB[4], ds[4] = {0.0f, 0.0f, 0.0f, 0.0f};
    {
        float xk[8];
        #pragma unroll
        for (int j = 0; j < 8; ++j) xk[j] = Xb[j].x;
        box8(xk, dk0[0], corA[0], ds[0]);
        #pragma unroll
        for (int j = 0; j < 8; ++j) xk[j] = Xb[j].y;
        box8(xk, dk0[1], corA[1], ds[1]);
        #pragma unroll
        for (int j = 0; j < 8; ++j) xk[j] = Xb[j].z;
        box8(xk, dk0[2], corA[2], ds[2]);
        #pragma unroll
        for (int j = 0; j < 8; ++j) xk[j] = Xb[j].w;
        box8(xk, dk0[3], corA[3], ds[3]);

        #pragma unroll
        for (int j = 0; j < 8; ++j) xk[j] = Xb[8 + j].x;
        box8(xk, dk1[0], corB[0], ds[0]);
        #pragma unroll
        for (int j = 0; j < 8; ++j) xk[j] = Xb[8 + j].y;
        box8(xk, dk1[1], corB[1], ds[1]);
        #pragma unroll
        for (int j = 0; j < 8; ++j) xk[j] = Xb[8 + j].z;
        box8(xk, dk1[2], corB[2], ds[2]);
        #pragma unroll
        for (int j = 0; j < 8; ++j) xk[j] = Xb[8 + j].w;
        box8(xk, dk1[3], corB[3], ds[3]);
    }

    // ---- cross-half merge via LDS (SoA float4: conflict-free b128) ----
    __shared__ float4 s_ns[256], s_xm[256], s_xl[256],
                      s_cA[256], s_cB[256], s_ds[256];
    if (h == 1) {
        s_ns[u] = make_float4(ns[0], ns[1], ns[2], ns[3]);
        s_xm[u] = make_float4(xm[0], xm[1], xm[2], xm[3]);
        s_xl[u] = make_float4(xlab[0], xlab[1], xlab[2], xlab[3]);
        s_cA[u] = make_float4(corA[0], corA[1], corA[2], corA[3]);
        s_cB[u] = make_float4(corB[0], corB[1], corB[2], corB[3]);
        s_ds[u] = make_float4(ds[0], ds[1], ds[2], ds[3]);
    }
    __syncthreads();

    float v0 = 0.0f, v1 = 0.0f, v2 = 0.0f, v3 = 0.0f;
    if (h == 0) {
        const float4 lw4 = *(const float4*)(label_weights + n0);
        const float lwv[4] = {lw4.x, lw4.y, lw4.z, lw4.w};
        const float4 q_ns = s_ns[u], q_xm = s_xm[u], q_xl = s_xl[u],
                     q_cA = s_cA[u], q_cB = s_cB[u], q_ds = s_ds[u];
        const float ns1[4] = {q_ns.x, q_ns.y, q_ns.z, q_ns.w};
        const float xm1[4] = {q_xm.x, q_xm.y, q_xm.z, q_xm.w};
        const float xl1[4] = {q_xl.x, q_xl.y, q_xl.z, q_xl.w};
        const float c2a[4] = {q_cA.x, q_cA.y, q_cA.z, q_cA.w};
        const float c3a[4] = {q_cB.x, q_cB.y, q_cB.z, q_cB.w};
        const float ds1[4] = {q_ds.x, q_ds.y, q_ds.z, q_ds.w};

        #pragma unroll
        for (int i = 0; i < 4; ++i) {
            const int lc = labv[i];
            const bool pos = (lc >= 0) && (lc < NUM_CLASSES);
            const float xmax_all = fmaxf(xm[i], xm1[i]);
            const float ns_all   = ns[i] + ns1[i];
            const float xl_sel   = (lc < CPH) ? xlab[i] : xl1[i];
            const float ds_all   = ds[i] + ds1[i];

            const float wt = pos ? frcp(1.0f + fexp(-xmax_all)) : 0.0f;

            const float px0 = cx[i] - corA[i], py0 = cy[i] - corB[i];
            const float px1 = cx[i] + c2a[i],  py1 = cy[i] + c3a[i];

            const float ilx = fmaxf(px0, tx0[i]), ily = fmaxf(py0, ty0[i]);
            const float irx = fminf(px1, tx1[i]), iry = fminf(py1, ty1[i]);
            const float iw = fmaxf(irx - ilx, 0.0f), ih = fmaxf(iry - ily, 0.0f);
            const float overlap = iw * ih;
            const float ap = (px1 - px0) * (py1 - py0);
            const float at = (tx1[i] - tx0[i]) * (ty1[i] - ty0[i]);
            const float uni = fmaxf(ap + at - overlap, 1e-6f);
            const float iou = overlap * frcp(uni);

            const float elx = fminf(px0, tx0[i]), ely = fminf(py0, ty0[i]);
            const float erx = fmaxf(px1, tx1[i]), ery = fmaxf(py1, ty1[i]);
            const float ew = fmaxf(erx - elx, 0.0f), eh = fmaxf(ery - ely, 0.0f);
            const float earea = fmaxf(ew * eh, 1e-6f);
            const float giou = iou - (earea - uni) * frcp(earea);

            const float score = pos ? iou : 0.0f;
            float row = ns_all;
            if (pos) {
                const float ee = fexp(-xl_sel);
                const float s  = frcp(1.0f + ee);      // sigmoid(x_label)
                const float sp = xl_sel - flog(s);     // softplus(x_label)
                const float negterm = sp * s * s;
                const float sf = score - s;
                const float posl = (sp - xl_sel * score) * sf * sf;
                row = row - negterm + posl;
            }

            v0 += row * lwv[i];
            v1 += (1.0f - giou) * wt;
            v2 += ds_all * wt;
            v3 += wt;
        }
    }

    v0 *= inv_nts;
    v1 *= 2.0f;
    v2 *= 0.0625f;     // 0.25 / 4

    // ---------------- reduction ----------------
    #pragma unroll
    for (int off = 32; off > 0; off >>= 1) {
        v0 += __shfl_down(v0, off);
        v1 += __shfl_down(v1, off);
        v2 += __shfl_down(v2, off);
        v3 += __shfl_down(v3, off);
    }

    __shared__ float smr[8][4];   // [wave][channel]
    const int w    = tib >> 6;
    const int lane = tib & 63;
    if (lane == 0) {
        smr[w][0] = v0; smr[w][1] = v1;
        smr[w][2] = v2; smr[w][3] = v3;
    }
    __syncthreads();
    if (tib == 0) {
        float s0 = 0.0f, s1 = 0.0f, s2 = 0.0f, s3 = 0.0f;
        #pragma unroll
        for (int i = 0; i < 8; ++i) {
            s0 += smr[i][0]; s1 += smr[i][1];
            s2 += smr[i][2]; s3 += smr[i][3];
        }
        atomicAdd(&out[0], s0);
        atomicAdd(&out[1], s1);
        atomicAdd(&out[2], s2);
        atomicAdd(&out[3], s3);
    }
}

extern "C" void kernel_launch(void* const* d_in, const int* in_sizes, int n_in,
                              void* d_out, int out_size, void* d_ws, size_t ws_size,
                              hipStream_t stream) {
    const float* anchors       = (const float*)d_in[0];
    const float* cls_score     = (const float*)d_in[1];
    const float* bbox_pred     = (const float*)d_in[2];
    const float* label_weights = (const float*)d_in[3];
    const float* bbox_targets  = (const float*)d_in[4];
    const int*   labels        = (const int*)d_in[5];
    const int*   nts_p         = (const int*)d_in[6];
    const int*   stride_p      = (const int*)d_in[7];
    float* out = (float*)d_out;

    const int N = in_sizes[5];  // labels count = B*H*W

    hipMemsetAsync(d_out, 0, 4 * sizeof(float), stream);

    const int grid = N / APB;                 // 256 blocks
    nanodet_loss_kernel<<<grid, BLOCK, 0, stream>>>(
        anchors, cls_score, bbox_pred, label_weights, bbox_targets,
        labels, nts_p, stride_p, out);
}